// Round 9
// baseline (833.836 us; speedup 1.0000x reference)
//
#include <hip/hip_runtime.h>
#include <math.h>

#define NN 50000      // nodes
#define NE 800000     // edges
#define NP 200000     // link pairs
#define NF 128        // feature dim
#define NEDGE_TOT (NE + NN)   // edges + self loops
#define NBLK 196              // ceil(NN/256)
#define NBK 64                // dst-range buckets
#define DPB 782               // dsts per bucket
#define BKCAP 16384           // bucket capacity
#define EPB 2048              // edges per Phase-A block

typedef __attribute__((ext_vector_type(8))) short short8;
typedef __attribute__((ext_vector_type(4))) float float4v;

// ---- bf16 helpers (manual, RNE) ----
__device__ __forceinline__ float bf_lo(unsigned u) { return __uint_as_float(u << 16); }
__device__ __forceinline__ float bf_hi(unsigned u) { return __uint_as_float(u & 0xffff0000u); }
__device__ __forceinline__ unsigned short f2bf(float f) {
    unsigned u = __float_as_uint(f);
    return (unsigned short)((u + 0x7fffu + ((u >> 16) & 1u)) >> 16);
}
__device__ __forceinline__ unsigned pack2bf(float a, float b) {
    return (unsigned)f2bf(a) | ((unsigned)f2bf(b) << 16);
}
__device__ __forceinline__ float i8f(unsigned v, int sh) {
    return (float)(signed char)(v >> sh);
}

// ---------------------------------------------------------------------------
// degree count + scan (row_ptr, dinv)
// ---------------------------------------------------------------------------
__global__ __launch_bounds__(256) void init_cnt_k(int* __restrict__ cnt) {
    int i = blockIdx.x * 256 + threadIdx.x;
    if (i < NN) cnt[i] = 1;  // self-loop
}

__global__ __launch_bounds__(256) void count_k(const int* __restrict__ ei,
                                               int* __restrict__ cnt) {
    int e = blockIdx.x * 256 + threadIdx.x;
    if (e < NE) atomicAdd(&cnt[ei[NE + e]], 1);
}

__global__ __launch_bounds__(256) void scan_reduce_k(const int* __restrict__ cnt,
                                                     int* __restrict__ bsum,
                                                     float* __restrict__ dinv) {
    __shared__ int s[256];
    int t = threadIdx.x;
    int idx = blockIdx.x * 256 + t;
    int v = (idx < NN) ? cnt[idx] : 0;
    if (idx < NN) dinv[idx] = rsqrtf((float)v);
    s[t] = v;
    __syncthreads();
    for (int off = 128; off > 0; off >>= 1) {
        if (t < off) s[t] += s[t + off];
        __syncthreads();
    }
    if (t == 0) bsum[blockIdx.x] = s[0];
}

__global__ __launch_bounds__(256) void scan_bsums_k(const int* __restrict__ bsum,
                                                    int* __restrict__ boff) {
    __shared__ int s[256];
    int t = threadIdx.x;
    int v = (t < NBLK) ? bsum[t] : 0;
    s[t] = v;
    __syncthreads();
    for (int off = 1; off < 256; off <<= 1) {
        int add = (t >= off) ? s[t - off] : 0;
        __syncthreads();
        s[t] += add;
        __syncthreads();
    }
    if (t < NBLK) boff[t] = s[t] - v;
}

__global__ __launch_bounds__(256) void scan_down_k(const int* __restrict__ cnt,
                                                   const int* __restrict__ boff,
                                                   int* __restrict__ row_ptr) {
    __shared__ int s[256];
    int t = threadIdx.x;
    int idx = blockIdx.x * 256 + t;
    int v = (idx < NN) ? cnt[idx] : 0;
    s[t] = v;
    __syncthreads();
    for (int off = 1; off < 256; off <<= 1) {
        int add = (t >= off) ? s[t - off] : 0;
        __syncthreads();
        s[t] += add;
        __syncthreads();
    }
    int excl = s[t] - v + boff[blockIdx.x];
    if (idx < NN) {
        row_ptr[idx] = excl;
        if (idx == NN - 1) row_ptr[NN] = excl + v;
    }
}

// ---------------------------------------------------------------------------
// Two-phase binned CSR build (round 8, verified).
// ---------------------------------------------------------------------------
__global__ __launch_bounds__(256) void bin_k(const int* __restrict__ ei,
                                             int* __restrict__ gtail,
                                             int2* __restrict__ gbk) {
    __shared__ int cntA[NBK], baseA[NBK], gposA[NBK];
    __shared__ int2 stage[EPB];
    int tid = threadIdx.x;
    int ebase = blockIdx.x * EPB;
    int sv[8], dv[8], lp8[8], bk8[8];
    bool val[8];
    if (tid < NBK) cntA[tid] = 0;
    __syncthreads();
#pragma unroll
    for (int k = 0; k < 8; ++k) {
        int e = ebase + k * 256 + tid;
        val[k] = (e < NEDGE_TOT);
        if (val[k]) {
            int s, d;
            if (e < NE) { s = ei[e]; d = ei[NE + e]; }
            else        { s = d = e - NE; }
            sv[k] = s; dv[k] = d;
            bk8[k] = d / DPB;
            lp8[k] = atomicAdd(&cntA[bk8[k]], 1);
        }
    }
    __syncthreads();
    if (tid == 0) {
        int run = 0;
        for (int b = 0; b < NBK; ++b) { baseA[b] = run; run += cntA[b]; }
    }
    __syncthreads();
    if (tid < NBK && cntA[tid] > 0)
        gposA[tid] = atomicAdd(&gtail[tid], cntA[tid]);
    __syncthreads();
#pragma unroll
    for (int k = 0; k < 8; ++k)
        if (val[k]) {
            int2 r; r.x = sv[k]; r.y = dv[k];
            stage[baseA[bk8[k]] + lp8[k]] = r;
        }
    __syncthreads();
    int total = baseA[NBK - 1] + cntA[NBK - 1];
    for (int i = tid; i < total; i += 256) {
        int2 r = stage[i];
        int b = r.y / DPB;
        gbk[(size_t)b * BKCAP + gposA[b] + (i - baseA[b])] = r;
    }
}

__global__ __launch_bounds__(256) void build_k(const int* __restrict__ row_ptr,
                                               const int* __restrict__ gtail,
                                               const int2* __restrict__ gbk,
                                               int* __restrict__ cols) {
    __shared__ int wcur[DPB];
    int tid = threadIdx.x;
    int b = blockIdx.x;
    int d0 = b * DPB;
    for (int i = tid; i < DPB; i += 256) {
        int d = d0 + i;
        wcur[i] = (d < NN) ? row_ptr[d] : 0;
    }
    __syncthreads();
    int nb = gtail[b];
    const int2* src = gbk + (size_t)b * BKCAP;
    for (int t = tid; t < nb; t += 256) {
        int2 r = src[t];
        int pos = atomicAdd(&wcur[r.y - d0], 1);
        cols[pos] = r.x;
    }
}

// zero dummy rows (row NN) of the three int8 state buffers + their scales
// + bucket tails
__global__ __launch_bounds__(256) void zero_k(unsigned char* QA, unsigned char* QB,
                                              unsigned char* QC,
                                              float* sA, float* sB, float* sC,
                                              int* gtail) {
    int t = threadIdx.x;
    unsigned char* bufs[3] = {QA, QB, QC};
    if (t < 96)
        ((unsigned*)(bufs[t >> 5] + (size_t)NN * NF))[t & 31] = 0u;
    if (t == 96) sA[NN] = 0.f;
    if (t == 97) sB[NN] = 0.f;
    if (t == 98) sC[NN] = 0.f;
    if (t >= 128 && t < 128 + NBK) gtail[t - 128] = 0;
}

// W fp32 -> bf16 row-major
__global__ __launch_bounds__(256) void cast_w_k(const float* __restrict__ W,
                                                unsigned short* __restrict__ Wb) {
    int t = blockIdx.x * 256 + threadIdx.x;
    if (t >= 128 * 128 / 8) return;
    int i = t * 8;
    float4 f0 = *(const float4*)(W + i);
    float4 f1 = *(const float4*)(W + i + 4);
    uint4 q;
    q.x = pack2bf(f0.x, f0.y);
    q.y = pack2bf(f0.z, f0.w);
    q.z = pack2bf(f1.x, f1.y);
    q.w = pack2bf(f1.z, f1.w);
    *(uint4*)(Wb + i) = q;
}

// ---------------------------------------------------------------------------
// MFMA GEMM (verified fragment layouts, rounds 2-8): Yu = X @ W.T + b (bf16).
// ---------------------------------------------------------------------------
#define GPAD 136
template <bool F32IN>
__global__ __launch_bounds__(256) void gemm_mfma_k(const void* __restrict__ Xv,
                                                   const unsigned short* __restrict__ Wb,
                                                   const float* __restrict__ bias,
                                                   unsigned short* __restrict__ Yu,
                                                   int nrows) {
    __shared__ unsigned short sm[4 * 16 * GPAD];  // 17408 B
    int wave = threadIdx.x >> 6, lane = threadIdx.x & 63;
    int rbase = blockIdx.x * 64 + wave * 16;
    if (rbase >= nrows) return;
    int quad = lane >> 4, mn = lane & 15;
    float4v acc[8];
#pragma unroll
    for (int ft = 0; ft < 8; ++ft) acc[ft] = (float4v){0.f, 0.f, 0.f, 0.f};
#pragma unroll
    for (int kb = 0; kb < 128; kb += 32) {
        short8 a;
        if (F32IN) {
            const float* X = (const float*)Xv;
            float4 f0 = *(const float4*)(X + (size_t)(rbase + mn) * NF + kb + quad * 8);
            float4 f1 = *(const float4*)(X + (size_t)(rbase + mn) * NF + kb + quad * 8 + 4);
            a[0] = (short)f2bf(f0.x); a[1] = (short)f2bf(f0.y);
            a[2] = (short)f2bf(f0.z); a[3] = (short)f2bf(f0.w);
            a[4] = (short)f2bf(f1.x); a[5] = (short)f2bf(f1.y);
            a[6] = (short)f2bf(f1.z); a[7] = (short)f2bf(f1.w);
        } else {
            const unsigned short* X = (const unsigned short*)Xv;
            a = *(const short8*)(X + (size_t)(rbase + mn) * NF + kb + quad * 8);
        }
#pragma unroll
        for (int ft = 0; ft < 8; ++ft) {
            short8 b = *(const short8*)(Wb + (size_t)(ft * 16 + mn) * NF + kb + quad * 8);
            acc[ft] = __builtin_amdgcn_mfma_f32_16x16x32_bf16(a, b, acc[ft], 0, 0, 0);
        }
    }
    unsigned short* smw = sm + wave * 16 * GPAD;
#pragma unroll
    for (int ft = 0; ft < 8; ++ft) {
        float bv = bias[ft * 16 + mn];
#pragma unroll
        for (int r = 0; r < 4; ++r)
            smw[(quad * 4 + r) * GPAD + ft * 16 + mn] = f2bf(acc[ft][r] + bv);
    }
    __syncthreads();
#pragma unroll
    for (int t = 0; t < 4; ++t) {
        int rl = t * 4 + quad;
        uint4 q = *(const uint4*)(smw + rl * GPAD + mn * 8);
        *(uint4*)(Yu + (size_t)(rbase + rl) * NF + mn * 8) = q;
    }
}

// ---------------------------------------------------------------------------
// quant_k: Q[v] = int8(dinv[v]*Yu[v] / s_v), s_v = rowmax/127 (per-row scale).
// 16 lanes per node (lane li owns feats li*8..li*8+7).
// ---------------------------------------------------------------------------
__global__ __launch_bounds__(256) void quant_k(const unsigned short* __restrict__ Yu,
                                               const float* __restrict__ dinv,
                                               unsigned char* __restrict__ Q,
                                               float* __restrict__ scl) {
    int node = (blockIdx.x * 256 + threadIdx.x) >> 4;
    int li = threadIdx.x & 15;
    if (node >= NN) return;
    float g = dinv[node];
    uint4 xq = *((const uint4*)(Yu + (size_t)node * NF) + li);
    float h0 = g * bf_lo(xq.x), h1 = g * bf_hi(xq.x);
    float h2 = g * bf_lo(xq.y), h3 = g * bf_hi(xq.y);
    float h4 = g * bf_lo(xq.z), h5 = g * bf_hi(xq.z);
    float h6 = g * bf_lo(xq.w), h7 = g * bf_hi(xq.w);
    float mx = fmaxf(fmaxf(fmaxf(fabsf(h0), fabsf(h1)), fmaxf(fabsf(h2), fabsf(h3))),
                     fmaxf(fmaxf(fabsf(h4), fabsf(h5)), fmaxf(fabsf(h6), fabsf(h7))));
#pragma unroll
    for (int off = 1; off < 16; off <<= 1)
        mx = fmaxf(mx, __shfl_xor(mx, off, 64));
    float smax = fmaxf(mx, 1e-20f);
    float inv = 127.0f / smax;
    uint2 q;
    q.x = ((unsigned)((int)rintf(h0 * inv)) & 255u)
        | ((unsigned)((int)rintf(h1 * inv)) & 255u) << 8
        | ((unsigned)((int)rintf(h2 * inv)) & 255u) << 16
        | ((unsigned)((int)rintf(h3 * inv)) & 255u) << 24;
    q.y = ((unsigned)((int)rintf(h4 * inv)) & 255u)
        | ((unsigned)((int)rintf(h5 * inv)) & 255u) << 8
        | ((unsigned)((int)rintf(h6 * inv)) & 255u) << 16
        | ((unsigned)((int)rintf(h7 * inv)) & 255u) << 24;
    *((uint2*)(Q + (size_t)node * NF) + li) = q;
    if (li == 0) scl[node] = smax * (1.0f / 127.0f);
}

// ---------------------------------------------------------------------------
// APPNP step on int8 scaled state Q[v] (hs = dinv*h, per-row scale scl):
//   A = sum_e scl[col_e] * Q[col_e]  ;  h_new = 0.9*dinv[v]*A + 0.1*x0[v]
//   mode 0: re-quantize dinv*h_new -> (oQ, oscl)
//   mode 1: out = relu(h_new) bf16   mode 2: relu + fused pair projection
// One 64-lane wave per node; 4 groups x 16 lanes; uint2/lane = 128 B int8 row
// per group -> 4 edges per gather instruction, x2 unrolled; round-up batches
// gather the hot zeroed dummy row NN (scl=0). fp32 accumulation.
// ---------------------------------------------------------------------------
__global__ __launch_bounds__(256) void appnp_q_k(const unsigned char* __restrict__ Q,
                                                 const float* __restrict__ scl,
                                                 const unsigned short* __restrict__ x0,
                                                 const float* __restrict__ dinv,
                                                 unsigned char* __restrict__ oQ,
                                                 float* __restrict__ oscl,
                                                 unsigned short* __restrict__ outbf,
                                                 const int* __restrict__ row_ptr,
                                                 const int* __restrict__ cols,
                                                 int mode,
                                                 const float* __restrict__ W3,
                                                 float4* __restrict__ puv) {
    int wid = (blockIdx.x * 256 + threadIdx.x) >> 6;
    int lane = threadIdx.x & 63;
    if (wid >= NN) return;
    int g4 = lane >> 4, li = lane & 15;
    int beg = row_ptr[wid], end = row_ptr[wid + 1];
    float a0 = 0.f, a1 = 0.f, a2 = 0.f, a3 = 0.f;
    float a4 = 0.f, a5 = 0.f, a6 = 0.f, a7 = 0.f;
    for (int e = beg; e < end; e += 64) {
        int m = end - e;
        if (m > 64) m = 64;
        int c = (lane < m) ? cols[e + lane] : NN;  // NN = zero row, scl 0
        float sv = scl[c];
        for (int j = 0; j < m; j += 8) {
            int cj0 = __shfl(c, j + g4, 64);
            float sj0 = __shfl(sv, j + g4, 64);
            int cj1 = __shfl(c, j + 4 + g4, 64);
            float sj1 = __shfl(sv, j + 4 + g4, 64);
            uint2 q0 = *((const uint2*)(Q + (size_t)cj0 * NF) + li);
            uint2 q1 = *((const uint2*)(Q + (size_t)cj1 * NF) + li);
            a0 += sj0 * i8f(q0.x, 0);  a1 += sj0 * i8f(q0.x, 8);
            a2 += sj0 * i8f(q0.x, 16); a3 += sj0 * i8f(q0.x, 24);
            a4 += sj0 * i8f(q0.y, 0);  a5 += sj0 * i8f(q0.y, 8);
            a6 += sj0 * i8f(q0.y, 16); a7 += sj0 * i8f(q0.y, 24);
            a0 += sj1 * i8f(q1.x, 0);  a1 += sj1 * i8f(q1.x, 8);
            a2 += sj1 * i8f(q1.x, 16); a3 += sj1 * i8f(q1.x, 24);
            a4 += sj1 * i8f(q1.y, 0);  a5 += sj1 * i8f(q1.y, 8);
            a6 += sj1 * i8f(q1.y, 16); a7 += sj1 * i8f(q1.y, 24);
        }
    }
#pragma unroll
    for (int off = 16; off < 64; off <<= 1) {
        a0 += __shfl_xor(a0, off, 64);
        a1 += __shfl_xor(a1, off, 64);
        a2 += __shfl_xor(a2, off, 64);
        a3 += __shfl_xor(a3, off, 64);
        a4 += __shfl_xor(a4, off, 64);
        a5 += __shfl_xor(a5, off, 64);
        a6 += __shfl_xor(a6, off, 64);
        a7 += __shfl_xor(a7, off, 64);
    }
    if (g4 != 0) return;
    float g = dinv[wid];
    float s9 = 0.9f * g;
    uint4 xq = *((const uint4*)(x0 + (size_t)wid * NF) + li);
    float h0 = s9 * a0 + 0.1f * bf_lo(xq.x);
    float h1 = s9 * a1 + 0.1f * bf_hi(xq.x);
    float h2 = s9 * a2 + 0.1f * bf_lo(xq.y);
    float h3 = s9 * a3 + 0.1f * bf_hi(xq.y);
    float h4 = s9 * a4 + 0.1f * bf_lo(xq.z);
    float h5 = s9 * a5 + 0.1f * bf_hi(xq.z);
    float h6 = s9 * a6 + 0.1f * bf_lo(xq.w);
    float h7 = s9 * a7 + 0.1f * bf_hi(xq.w);
    if (mode == 0) {
        // re-quantize dinv*h_new
        h0 *= g; h1 *= g; h2 *= g; h3 *= g;
        h4 *= g; h5 *= g; h6 *= g; h7 *= g;
        float mx = fmaxf(fmaxf(fmaxf(fabsf(h0), fabsf(h1)), fmaxf(fabsf(h2), fabsf(h3))),
                         fmaxf(fmaxf(fabsf(h4), fabsf(h5)), fmaxf(fabsf(h6), fabsf(h7))));
#pragma unroll
        for (int off = 1; off < 16; off <<= 1)
            mx = fmaxf(mx, __shfl_xor(mx, off, 64));
        float smax = fmaxf(mx, 1e-20f);
        float inv = 127.0f / smax;
        uint2 q;
        q.x = ((unsigned)((int)rintf(h0 * inv)) & 255u)
            | ((unsigned)((int)rintf(h1 * inv)) & 255u) << 8
            | ((unsigned)((int)rintf(h2 * inv)) & 255u) << 16
            | ((unsigned)((int)rintf(h3 * inv)) & 255u) << 24;
        q.y = ((unsigned)((int)rintf(h4 * inv)) & 255u)
            | ((unsigned)((int)rintf(h5 * inv)) & 255u) << 8
            | ((unsigned)((int)rintf(h6 * inv)) & 255u) << 16
            | ((unsigned)((int)rintf(h7 * inv)) & 255u) << 24;
        *((uint2*)(oQ + (size_t)wid * NF) + li) = q;
        if (li == 0) oscl[wid] = smax * (1.0f / 127.0f);
    } else {
        h0 = fmaxf(h0, 0.f); h1 = fmaxf(h1, 0.f);
        h2 = fmaxf(h2, 0.f); h3 = fmaxf(h3, 0.f);
        h4 = fmaxf(h4, 0.f); h5 = fmaxf(h5, 0.f);
        h6 = fmaxf(h6, 0.f); h7 = fmaxf(h7, 0.f);
        if (mode == 1) {
            uint4 oq;
            oq.x = pack2bf(h0, h1);
            oq.y = pack2bf(h2, h3);
            oq.z = pack2bf(h4, h5);
            oq.w = pack2bf(h6, h7);
            *((uint4*)(outbf + (size_t)wid * NF) + li) = oq;
        } else {
            int fb = li * 8;
            float4 wu0a = *(const float4*)(W3 + fb);
            float4 wu0b = *(const float4*)(W3 + fb + 4);
            float4 wv0a = *(const float4*)(W3 + 128 + fb);
            float4 wv0b = *(const float4*)(W3 + 128 + fb + 4);
            float4 wu1a = *(const float4*)(W3 + 256 + fb);
            float4 wu1b = *(const float4*)(W3 + 256 + fb + 4);
            float4 wv1a = *(const float4*)(W3 + 384 + fb);
            float4 wv1b = *(const float4*)(W3 + 384 + fb + 4);
            float du0 = h0 * wu0a.x + h1 * wu0a.y + h2 * wu0a.z + h3 * wu0a.w
                      + h4 * wu0b.x + h5 * wu0b.y + h6 * wu0b.z + h7 * wu0b.w;
            float du1 = h0 * wu1a.x + h1 * wu1a.y + h2 * wu1a.z + h3 * wu1a.w
                      + h4 * wu1b.x + h5 * wu1b.y + h6 * wu1b.z + h7 * wu1b.w;
            float dv0 = h0 * wv0a.x + h1 * wv0a.y + h2 * wv0a.z + h3 * wv0a.w
                      + h4 * wv0b.x + h5 * wv0b.y + h6 * wv0b.z + h7 * wv0b.w;
            float dv1 = h0 * wv1a.x + h1 * wv1a.y + h2 * wv1a.z + h3 * wv1a.w
                      + h4 * wv1b.x + h5 * wv1b.y + h6 * wv1b.z + h7 * wv1b.w;
#pragma unroll
            for (int off = 1; off < 16; off <<= 1) {
                du0 += __shfl_xor(du0, off, 64);
                du1 += __shfl_xor(du1, off, 64);
                dv0 += __shfl_xor(dv0, off, 64);
                dv1 += __shfl_xor(dv1, off, 64);
            }
            if (li == 0) puv[wid] = make_float4(du0, du1, dv0, dv1);
        }
    }
}

// ---------------------------------------------------------------------------
// Pair head from precomputed projections: one thread per pair.
// ---------------------------------------------------------------------------
__global__ __launch_bounds__(256) void pair2_k(const float4* __restrict__ puv,
                                               const int2* __restrict__ index,
                                               const float* __restrict__ b3,
                                               float* __restrict__ outp) {
    int p = blockIdx.x * 256 + threadIdx.x;
    if (p >= NP) return;
    int2 uv = index[p];
    float4 a = puv[uv.x];
    float4 b = puv[uv.y];
    float s0 = a.x + b.z + b3[0];
    float s1 = a.y + b.w + b3[1];
    float m = fmaxf(s0, s1);
    float lse = m + logf(expf(s0 - m) + expf(s1 - m));
    *(float2*)(outp + (size_t)p * 2) = make_float2(s0 - lse, s1 - lse);
}

// ---------------------------------------------------------------------------
// Launch
// ---------------------------------------------------------------------------
extern "C" void kernel_launch(void* const* d_in, const int* in_sizes, int n_in,
                              void* d_out, int out_size, void* d_ws, size_t ws_size,
                              hipStream_t stream) {
    const float* x  = (const float*)d_in[0];
    const int* ei   = (const int*)d_in[1];
    const int* idx  = (const int*)d_in[2];
    const float* W1 = (const float*)d_in[3];
    const float* b1 = (const float*)d_in[4];
    const float* W2 = (const float*)d_in[5];
    const float* b2 = (const float*)d_in[6];
    const float* W3 = (const float*)d_in[7];
    const float* b3 = (const float*)d_in[8];
    float* out = (float*)d_out;

    char* ws = (char*)d_ws;
    size_t off = 0;
    auto alloc = [&](size_t bytes) -> void* {
        void* p = ws + off;
        off = (off + bytes + 255) & ~(size_t)255;
        return p;
    };
    const size_t QROWS = (size_t)(NN + 1) * NF;  // +1: zero dummy row
    int*   cnt     = (int*)  alloc(NN * sizeof(int));
    float* dinv    = (float*)alloc(NN * sizeof(float));
    int*   row_ptr = (int*)  alloc((NN + 1) * sizeof(int));
    int*   bsum    = (int*)  alloc(NBLK * sizeof(int));
    int*   boff    = (int*)  alloc(NBLK * sizeof(int));
    int*   gtail   = (int*)  alloc(NBK * sizeof(int));
    int2*  gbk     = (int2*) alloc((size_t)NBK * BKCAP * sizeof(int2));  // 8 MB
    int*   cols    = (int*)  alloc((size_t)NEDGE_TOT * sizeof(int));
    float4* puv    = (float4*)alloc((size_t)NN * sizeof(float4));
    unsigned short* Wb1 = (unsigned short*)alloc(128 * 128 * 2);
    unsigned short* Wb2 = (unsigned short*)alloc(128 * 128 * 2);
    unsigned short* Yu1 = (unsigned short*)alloc((size_t)NN * NF * 2);
    unsigned short* Yu2 = (unsigned short*)alloc((size_t)NN * NF * 2);
    unsigned short* Hrelu = (unsigned short*)alloc((size_t)NN * NF * 2);
    unsigned char* QA = (unsigned char*)alloc(QROWS);
    unsigned char* QB = (unsigned char*)alloc(QROWS);
    unsigned char* QC = (unsigned char*)alloc(QROWS);
    float* sA = (float*)alloc((NN + 1) * sizeof(float));
    float* sB = (float*)alloc((NN + 1) * sizeof(float));
    float* sC = (float*)alloc((NN + 1) * sizeof(float));

    const int gN    = (NN + 255) / 256;
    const int gE    = (NE + 255) / 256;
    const int gBin  = (NEDGE_TOT + EPB - 1) / EPB;
    const int gGemm = (NN + 63) / 64;
    const int gQnt  = (NN * 16 + 255) / 256;
    const int gStep = (NN * 64 + 255) / 256;
    const int gPair = (NP + 255) / 256;

    // ---- weights + gcn_norm + binned CSR ----
    cast_w_k<<<8, 256, 0, stream>>>(W1, Wb1);
    cast_w_k<<<8, 256, 0, stream>>>(W2, Wb2);
    zero_k<<<1, 256, 0, stream>>>(QA, QB, QC, sA, sB, sC, gtail);
    init_cnt_k<<<gN, 256, 0, stream>>>(cnt);
    count_k<<<gE, 256, 0, stream>>>(ei, cnt);
    scan_reduce_k<<<NBLK, 256, 0, stream>>>(cnt, bsum, dinv);
    scan_bsums_k<<<1, 256, 0, stream>>>(bsum, boff);
    scan_down_k<<<NBLK, 256, 0, stream>>>(cnt, boff, row_ptr);
    bin_k<<<gBin, 256, 0, stream>>>(ei, gtail, gbk);
    build_k<<<NBK, 256, 0, stream>>>(row_ptr, gtail, gbk, cols);

    unsigned char* Qs[3] = {QA, QB, QC};
    float* ss[3] = {sA, sB, sC};

    // ---- layer 1 ----
    gemm_mfma_k<true><<<gGemm, 256, 0, stream>>>(x, Wb1, b1, Yu1, NN);
    quant_k<<<gQnt, 256, 0, stream>>>(Yu1, dinv, QA, sA);
    {
        int cur = 0;
        for (int k = 0; k < 10; ++k) {
            int nxt = (k & 1) ? 2 : 1;  // alternate QB/QC
            appnp_q_k<<<gStep, 256, 0, stream>>>(
                Qs[cur], ss[cur], Yu1, dinv, Qs[nxt], ss[nxt], Hrelu,
                row_ptr, cols, (k == 9) ? 1 : 0, W3, puv);
            cur = nxt;
        }
    }
    // ---- layer 2 ----
    gemm_mfma_k<false><<<gGemm, 256, 0, stream>>>(Hrelu, Wb2, b2, Yu2, NN);
    quant_k<<<gQnt, 256, 0, stream>>>(Yu2, dinv, QA, sA);
    {
        int cur = 0;
        for (int k = 0; k < 10; ++k) {
            int nxt = (k & 1) ? 2 : 1;
            appnp_q_k<<<gStep, 256, 0, stream>>>(
                Qs[cur], ss[cur], Yu2, dinv, Qs[nxt], ss[nxt], Hrelu,
                row_ptr, cols, (k == 9) ? 2 : 0, W3, puv);
            cur = nxt;
        }
    }
    // ---- pair head ----
    pair2_k<<<gPair, 256, 0, stream>>>(puv, (const int2*)idx, b3, out);
}

// Round 10
// 830.741 us; speedup vs baseline: 1.0037x; 1.0037x over previous
//
#include <hip/hip_runtime.h>
#include <math.h>

#define NN 50000      // nodes
#define NE 800000     // edges
#define NP 200000     // link pairs
#define NF 128        // feature dim
#define NEDGE_TOT (NE + NN)   // edges + self loops
#define NBLK 196              // ceil(NN/256)
#define NBK 64                // dst-range buckets
#define DPB 782               // dsts per bucket
#define BKCAP 16384           // bucket capacity
#define EPB 2048              // edges per Phase-A block

typedef __attribute__((ext_vector_type(8))) short short8;
typedef __attribute__((ext_vector_type(4))) float float4v;
typedef __attribute__((ext_vector_type(2))) _Float16 h2;

// ---- bf16 helpers (manual, RNE) ----
__device__ __forceinline__ float bf_lo(unsigned u) { return __uint_as_float(u << 16); }
__device__ __forceinline__ float bf_hi(unsigned u) { return __uint_as_float(u & 0xffff0000u); }
__device__ __forceinline__ unsigned short f2bf(float f) {
    unsigned u = __float_as_uint(f);
    return (unsigned short)((u + 0x7fffu + ((u >> 16) & 1u)) >> 16);
}
__device__ __forceinline__ unsigned pack2bf(float a, float b) {
    return (unsigned)f2bf(a) | ((unsigned)f2bf(b) << 16);
}

// ---- f16 helpers ----
__device__ __forceinline__ h2 u2h2(unsigned u) {
    union { unsigned u; h2 h; } c; c.u = u; return c.h;
}
__device__ __forceinline__ unsigned h22u(h2 h) {
    union { unsigned u; h2 h; } c; c.h = h; return c.u;
}
__device__ __forceinline__ float h_lo(unsigned u) { return (float)u2h2(u).x; }
__device__ __forceinline__ float h_hi(unsigned u) { return (float)u2h2(u).y; }
__device__ __forceinline__ unsigned pack2h(float a, float b) {
    h2 h; h.x = (_Float16)a; h.y = (_Float16)b; return h22u(h);
}

// ---------------------------------------------------------------------------
// degree count + scan (row_ptr, dinv)
// ---------------------------------------------------------------------------
__global__ __launch_bounds__(256) void init_cnt_k(int* __restrict__ cnt) {
    int i = blockIdx.x * 256 + threadIdx.x;
    if (i < NN) cnt[i] = 1;  // self-loop
}

__global__ __launch_bounds__(256) void count_k(const int* __restrict__ ei,
                                               int* __restrict__ cnt) {
    int e = blockIdx.x * 256 + threadIdx.x;
    if (e < NE) atomicAdd(&cnt[ei[NE + e]], 1);
}

__global__ __launch_bounds__(256) void scan_reduce_k(const int* __restrict__ cnt,
                                                     int* __restrict__ bsum,
                                                     float* __restrict__ dinv) {
    __shared__ int s[256];
    int t = threadIdx.x;
    int idx = blockIdx.x * 256 + t;
    int v = (idx < NN) ? cnt[idx] : 0;
    if (idx < NN) dinv[idx] = rsqrtf((float)v);
    s[t] = v;
    __syncthreads();
    for (int off = 128; off > 0; off >>= 1) {
        if (t < off) s[t] += s[t + off];
        __syncthreads();
    }
    if (t == 0) bsum[blockIdx.x] = s[0];
}

__global__ __launch_bounds__(256) void scan_bsums_k(const int* __restrict__ bsum,
                                                    int* __restrict__ boff) {
    __shared__ int s[256];
    int t = threadIdx.x;
    int v = (t < NBLK) ? bsum[t] : 0;
    s[t] = v;
    __syncthreads();
    for (int off = 1; off < 256; off <<= 1) {
        int add = (t >= off) ? s[t - off] : 0;
        __syncthreads();
        s[t] += add;
        __syncthreads();
    }
    if (t < NBLK) boff[t] = s[t] - v;
}

__global__ __launch_bounds__(256) void scan_down_k(const int* __restrict__ cnt,
                                                   const int* __restrict__ boff,
                                                   int* __restrict__ row_ptr) {
    __shared__ int s[256];
    int t = threadIdx.x;
    int idx = blockIdx.x * 256 + t;
    int v = (idx < NN) ? cnt[idx] : 0;
    s[t] = v;
    __syncthreads();
    for (int off = 1; off < 256; off <<= 1) {
        int add = (t >= off) ? s[t - off] : 0;
        __syncthreads();
        s[t] += add;
        __syncthreads();
    }
    int excl = s[t] - v + boff[blockIdx.x];
    if (idx < NN) {
        row_ptr[idx] = excl;
        if (idx == NN - 1) row_ptr[NN] = excl + v;
    }
}

// ---------------------------------------------------------------------------
// Two-phase binned CSR build (round 8, verified).
// ---------------------------------------------------------------------------
__global__ __launch_bounds__(256) void bin_k(const int* __restrict__ ei,
                                             int* __restrict__ gtail,
                                             int2* __restrict__ gbk) {
    __shared__ int cntA[NBK], baseA[NBK], gposA[NBK];
    __shared__ int2 stage[EPB];
    int tid = threadIdx.x;
    int ebase = blockIdx.x * EPB;
    int sv[8], dv[8], lp8[8], bk8[8];
    bool val[8];
    if (tid < NBK) cntA[tid] = 0;
    __syncthreads();
#pragma unroll
    for (int k = 0; k < 8; ++k) {
        int e = ebase + k * 256 + tid;
        val[k] = (e < NEDGE_TOT);
        if (val[k]) {
            int s, d;
            if (e < NE) { s = ei[e]; d = ei[NE + e]; }
            else        { s = d = e - NE; }
            sv[k] = s; dv[k] = d;
            bk8[k] = d / DPB;
            lp8[k] = atomicAdd(&cntA[bk8[k]], 1);
        }
    }
    __syncthreads();
    if (tid == 0) {
        int run = 0;
        for (int b = 0; b < NBK; ++b) { baseA[b] = run; run += cntA[b]; }
    }
    __syncthreads();
    if (tid < NBK && cntA[tid] > 0)
        gposA[tid] = atomicAdd(&gtail[tid], cntA[tid]);
    __syncthreads();
#pragma unroll
    for (int k = 0; k < 8; ++k)
        if (val[k]) {
            int2 r; r.x = sv[k]; r.y = dv[k];
            stage[baseA[bk8[k]] + lp8[k]] = r;
        }
    __syncthreads();
    int total = baseA[NBK - 1] + cntA[NBK - 1];
    for (int i = tid; i < total; i += 256) {
        int2 r = stage[i];
        int b = r.y / DPB;
        gbk[(size_t)b * BKCAP + gposA[b] + (i - baseA[b])] = r;
    }
}

__global__ __launch_bounds__(256) void build_k(const int* __restrict__ row_ptr,
                                               const int* __restrict__ gtail,
                                               const int2* __restrict__ gbk,
                                               int* __restrict__ cols) {
    __shared__ int wcur[DPB];
    int tid = threadIdx.x;
    int b = blockIdx.x;
    int d0 = b * DPB;
    for (int i = tid; i < DPB; i += 256) {
        int d = d0 + i;
        wcur[i] = (d < NN) ? row_ptr[d] : 0;
    }
    __syncthreads();
    int nb = gtail[b];
    const int2* src = gbk + (size_t)b * BKCAP;
    for (int t = tid; t < nb; t += 256) {
        int2 r = src[t];
        int pos = atomicAdd(&wcur[r.y - d0], 1);
        cols[pos] = r.x;
    }
}

// zero dummy rows (row NN) of the four f16 state buffers + bucket tails
__global__ __launch_bounds__(256) void zero_k(unsigned short* Ys1, unsigned short* Ys2,
                                              unsigned short* HA, unsigned short* HB,
                                              int* gtail) {
    int t = threadIdx.x;  // 256 threads; 4 rows x 64 uints
    unsigned short* bufs[4] = {Ys1, Ys2, HA, HB};
    unsigned short* b = bufs[t >> 6];
    ((unsigned*)(b + (size_t)NN * NF))[t & 63] = 0u;
    if (t < NBK) gtail[t] = 0;
}

// W fp32 -> bf16 row-major (GEMM B operand stays on verified bf16 MFMA path)
__global__ __launch_bounds__(256) void cast_w_k(const float* __restrict__ W,
                                                unsigned short* __restrict__ Wb) {
    int t = blockIdx.x * 256 + threadIdx.x;
    if (t >= 128 * 128 / 8) return;
    int i = t * 8;
    float4 f0 = *(const float4*)(W + i);
    float4 f1 = *(const float4*)(W + i + 4);
    uint4 q;
    q.x = pack2bf(f0.x, f0.y);
    q.y = pack2bf(f0.z, f0.w);
    q.z = pack2bf(f1.x, f1.y);
    q.w = pack2bf(f1.z, f1.w);
    *(uint4*)(Wb + i) = q;
}

// ---------------------------------------------------------------------------
// MFMA GEMM (verified bf16 fragment layouts, rounds 2-9): Y = X @ W.T + b.
// Dual f16 epilogue: Yu = unscaled f16 (x0 stream), Ys = dinv-scaled f16 hs0.
// LDS holds f16 this round (same u16 slots, pad 136).
// ---------------------------------------------------------------------------
#define GPAD 136
template <bool F32IN>
__global__ __launch_bounds__(256) void gemm_mfma_k(const void* __restrict__ Xv,
                                                   const unsigned short* __restrict__ Wb,
                                                   const float* __restrict__ bias,
                                                   const float* __restrict__ dinv,
                                                   unsigned short* __restrict__ Yu,
                                                   unsigned short* __restrict__ Ys,
                                                   int nrows) {
    __shared__ unsigned short sm[4 * 16 * GPAD];  // 17408 B
    int wave = threadIdx.x >> 6, lane = threadIdx.x & 63;
    int rbase = blockIdx.x * 64 + wave * 16;
    if (rbase >= nrows) return;
    int quad = lane >> 4, mn = lane & 15;
    float4v acc[8];
#pragma unroll
    for (int ft = 0; ft < 8; ++ft) acc[ft] = (float4v){0.f, 0.f, 0.f, 0.f};
#pragma unroll
    for (int kb = 0; kb < 128; kb += 32) {
        short8 a;
        if (F32IN) {
            const float* X = (const float*)Xv;
            float4 f0 = *(const float4*)(X + (size_t)(rbase + mn) * NF + kb + quad * 8);
            float4 f1 = *(const float4*)(X + (size_t)(rbase + mn) * NF + kb + quad * 8 + 4);
            a[0] = (short)f2bf(f0.x); a[1] = (short)f2bf(f0.y);
            a[2] = (short)f2bf(f0.z); a[3] = (short)f2bf(f0.w);
            a[4] = (short)f2bf(f1.x); a[5] = (short)f2bf(f1.y);
            a[6] = (short)f2bf(f1.z); a[7] = (short)f2bf(f1.w);
        } else {
            const unsigned short* X = (const unsigned short*)Xv;
            a = *(const short8*)(X + (size_t)(rbase + mn) * NF + kb + quad * 8);
        }
#pragma unroll
        for (int ft = 0; ft < 8; ++ft) {
            short8 b = *(const short8*)(Wb + (size_t)(ft * 16 + mn) * NF + kb + quad * 8);
            acc[ft] = __builtin_amdgcn_mfma_f32_16x16x32_bf16(a, b, acc[ft], 0, 0, 0);
        }
    }
    unsigned short* smw = sm + wave * 16 * GPAD;
#pragma unroll
    for (int ft = 0; ft < 8; ++ft) {
        float bv = bias[ft * 16 + mn];
#pragma unroll
        for (int r = 0; r < 4; ++r) {
            union { _Float16 h; unsigned short s; } cv;
            cv.h = (_Float16)(acc[ft][r] + bv);
            smw[(quad * 4 + r) * GPAD + ft * 16 + mn] = cv.s;
        }
    }
    __syncthreads();
#pragma unroll
    for (int t = 0; t < 4; ++t) {
        int rl = t * 4 + quad;
        int row = rbase + rl;
        uint4 q = *(const uint4*)(smw + rl * GPAD + mn * 8);
        *(uint4*)(Yu + (size_t)row * NF + mn * 8) = q;
        float g = dinv[row];
        uint4 qs;
        qs.x = pack2h(g * h_lo(q.x), g * h_hi(q.x));
        qs.y = pack2h(g * h_lo(q.y), g * h_hi(q.y));
        qs.z = pack2h(g * h_lo(q.z), g * h_hi(q.z));
        qs.w = pack2h(g * h_lo(q.w), g * h_hi(q.w));
        *(uint4*)(Ys + (size_t)row * NF + mn * 8) = qs;
    }
}

// ---------------------------------------------------------------------------
// APPNP step on f16 scaled state hs[v] = dinv[v]*h[v]:
//   A = sum_{e in row v} hs[col_e]   (packed v_pk_add_f16 — 1 instr / 2 feats)
//   h_new = 0.9*dinv[v]*A + 0.1*x0[v]
//   mode 0: out = dinv*h_new (f16) | mode 1: out = relu(h_new) (bf16, GEMM2 in)
//   mode 2: relu + fused pair projection -> puv
// One 64-lane wave per node; uint2/lane, 2 edges per 512 B gather instr;
// fixed 8-edge round-up batches; dummy slots gather the zeroed row NN.
// f16 accumulation (3 more mantissa bits than bf16; |sum| << 65504).
// ---------------------------------------------------------------------------
__global__ __launch_bounds__(256) void appnp_h_k(const unsigned short* __restrict__ hs,
                                                 const unsigned short* __restrict__ x0,
                                                 const float* __restrict__ dinv,
                                                 unsigned short* __restrict__ out,
                                                 const int* __restrict__ row_ptr,
                                                 const int* __restrict__ cols,
                                                 int mode,
                                                 const float* __restrict__ W3,
                                                 float4* __restrict__ puv) {
    int wid = (blockIdx.x * 256 + threadIdx.x) >> 6;
    int lane = threadIdx.x & 63;
    if (wid >= NN) return;
    int half = lane >> 5, li = lane & 31;
    int beg = row_ptr[wid], end = row_ptr[wid + 1];
    h2 a01; a01.x = (_Float16)0.f; a01.y = (_Float16)0.f;
    h2 a23 = a01;
    for (int e = beg; e < end; e += 64) {
        int m = end - e;
        if (m > 64) m = 64;
        int c = (lane < m) ? cols[e + lane] : NN;  // NN = zero row
        for (int j = 0; j < m; j += 8) {
            int c0 = __shfl(c, j + half, 64);
            int c1 = __shfl(c, j + 2 + half, 64);
            int c2 = __shfl(c, j + 4 + half, 64);
            int c3 = __shfl(c, j + 6 + half, 64);
            uint2 q0 = *((const uint2*)(hs + (size_t)c0 * NF) + li);
            uint2 q1 = *((const uint2*)(hs + (size_t)c1 * NF) + li);
            uint2 q2 = *((const uint2*)(hs + (size_t)c2 * NF) + li);
            uint2 q3 = *((const uint2*)(hs + (size_t)c3 * NF) + li);
            a01 += (u2h2(q0.x) + u2h2(q1.x)) + (u2h2(q2.x) + u2h2(q3.x));
            a23 += (u2h2(q0.y) + u2h2(q1.y)) + (u2h2(q2.y) + u2h2(q3.y));
        }
    }
    a01 += u2h2((unsigned)__shfl_xor((int)h22u(a01), 32, 64));
    a23 += u2h2((unsigned)__shfl_xor((int)h22u(a23), 32, 64));
    if (half != 0) return;
    float g = dinv[wid];
    float s9 = 0.9f * g;
    uint2 xq = *((const uint2*)(x0 + (size_t)wid * NF) + li);
    float h0 = s9 * (float)a01.x + 0.1f * h_lo(xq.x);
    float h1 = s9 * (float)a01.y + 0.1f * h_hi(xq.x);
    float h2v = s9 * (float)a23.x + 0.1f * h_lo(xq.y);
    float h3 = s9 * (float)a23.y + 0.1f * h_hi(xq.y);
    if (mode == 0) {
        uint2 oq;
        oq.x = pack2h(g * h0, g * h1);
        oq.y = pack2h(g * h2v, g * h3);
        *((uint2*)(out + (size_t)wid * NF) + li) = oq;
    } else {
        h0 = fmaxf(h0, 0.f); h1 = fmaxf(h1, 0.f);
        h2v = fmaxf(h2v, 0.f); h3 = fmaxf(h3, 0.f);
        if (mode == 1) {
            uint2 oq;
            oq.x = pack2bf(h0, h1);
            oq.y = pack2bf(h2v, h3);
            *((uint2*)(out + (size_t)wid * NF) + li) = oq;
        } else {
            int fb = li * 4;
            float4 wu0 = *(const float4*)(W3 + fb);
            float4 wv0 = *(const float4*)(W3 + 128 + fb);
            float4 wu1 = *(const float4*)(W3 + 256 + fb);
            float4 wv1 = *(const float4*)(W3 + 384 + fb);
            float du0 = h0 * wu0.x + h1 * wu0.y + h2v * wu0.z + h3 * wu0.w;
            float du1 = h0 * wu1.x + h1 * wu1.y + h2v * wu1.z + h3 * wu1.w;
            float dv0 = h0 * wv0.x + h1 * wv0.y + h2v * wv0.z + h3 * wv0.w;
            float dv1 = h0 * wv1.x + h1 * wv1.y + h2v * wv1.z + h3 * wv1.w;
#pragma unroll
            for (int off = 1; off < 32; off <<= 1) {
                du0 += __shfl_xor(du0, off, 64);
                du1 += __shfl_xor(du1, off, 64);
                dv0 += __shfl_xor(dv0, off, 64);
                dv1 += __shfl_xor(dv1, off, 64);
            }
            if (li == 0) puv[wid] = make_float4(du0, du1, dv0, dv1);
        }
    }
}

// ---------------------------------------------------------------------------
// Pair head from precomputed projections: one thread per pair.
// ---------------------------------------------------------------------------
__global__ __launch_bounds__(256) void pair2_k(const float4* __restrict__ puv,
                                               const int2* __restrict__ index,
                                               const float* __restrict__ b3,
                                               float* __restrict__ outp) {
    int p = blockIdx.x * 256 + threadIdx.x;
    if (p >= NP) return;
    int2 uv = index[p];
    float4 a = puv[uv.x];
    float4 b = puv[uv.y];
    float s0 = a.x + b.z + b3[0];
    float s1 = a.y + b.w + b3[1];
    float m = fmaxf(s0, s1);
    float lse = m + logf(expf(s0 - m) + expf(s1 - m));
    *(float2*)(outp + (size_t)p * 2) = make_float2(s0 - lse, s1 - lse);
}

// ---------------------------------------------------------------------------
// Launch
// ---------------------------------------------------------------------------
extern "C" void kernel_launch(void* const* d_in, const int* in_sizes, int n_in,
                              void* d_out, int out_size, void* d_ws, size_t ws_size,
                              hipStream_t stream) {
    const float* x  = (const float*)d_in[0];
    const int* ei   = (const int*)d_in[1];
    const int* idx  = (const int*)d_in[2];
    const float* W1 = (const float*)d_in[3];
    const float* b1 = (const float*)d_in[4];
    const float* W2 = (const float*)d_in[5];
    const float* b2 = (const float*)d_in[6];
    const float* W3 = (const float*)d_in[7];
    const float* b3 = (const float*)d_in[8];
    float* out = (float*)d_out;

    char* ws = (char*)d_ws;
    size_t off = 0;
    auto alloc = [&](size_t bytes) -> void* {
        void* p = ws + off;
        off = (off + bytes + 255) & ~(size_t)255;
        return p;
    };
    const size_t HROWS = (size_t)(NN + 1) * NF;  // +1: zero dummy row
    int*   cnt     = (int*)  alloc(NN * sizeof(int));
    float* dinv    = (float*)alloc(NN * sizeof(float));
    int*   row_ptr = (int*)  alloc((NN + 1) * sizeof(int));
    int*   bsum    = (int*)  alloc(NBLK * sizeof(int));
    int*   boff    = (int*)  alloc(NBLK * sizeof(int));
    int*   gtail   = (int*)  alloc(NBK * sizeof(int));
    int2*  gbk     = (int2*) alloc((size_t)NBK * BKCAP * sizeof(int2));  // 8 MB
    int*   cols    = (int*)  alloc((size_t)NEDGE_TOT * sizeof(int));
    float4* puv    = (float4*)alloc((size_t)NN * sizeof(float4));
    unsigned short* Wb1 = (unsigned short*)alloc(128 * 128 * 2);
    unsigned short* Wb2 = (unsigned short*)alloc(128 * 128 * 2);
    unsigned short* Yu1 = (unsigned short*)alloc(HROWS * 2);
    unsigned short* Ys1 = (unsigned short*)alloc(HROWS * 2);
    unsigned short* Yu2 = (unsigned short*)alloc(HROWS * 2);
    unsigned short* Ys2 = (unsigned short*)alloc(HROWS * 2);
    unsigned short* HA  = (unsigned short*)alloc(HROWS * 2);
    unsigned short* HB  = (unsigned short*)alloc(HROWS * 2);
    unsigned short* Hrelu = (unsigned short*)alloc((size_t)NN * NF * 2);

    const int gN    = (NN + 255) / 256;
    const int gE    = (NE + 255) / 256;
    const int gBin  = (NEDGE_TOT + EPB - 1) / EPB;
    const int gGemm = (NN + 63) / 64;            // wave per 16 rows
    const int gStep = (NN * 64 + 255) / 256;     // 64-lane wave per node
    const int gPair = (NP + 255) / 256;          // thread per pair

    // ---- weights + gcn_norm + binned CSR ----
    cast_w_k<<<8, 256, 0, stream>>>(W1, Wb1);
    cast_w_k<<<8, 256, 0, stream>>>(W2, Wb2);
    zero_k<<<1, 256, 0, stream>>>(Ys1, Ys2, HA, HB, gtail);
    init_cnt_k<<<gN, 256, 0, stream>>>(cnt);
    count_k<<<gE, 256, 0, stream>>>(ei, cnt);
    scan_reduce_k<<<NBLK, 256, 0, stream>>>(cnt, bsum, dinv);
    scan_bsums_k<<<1, 256, 0, stream>>>(bsum, boff);
    scan_down_k<<<NBLK, 256, 0, stream>>>(cnt, boff, row_ptr);
    bin_k<<<gBin, 256, 0, stream>>>(ei, gtail, gbk);
    build_k<<<NBK, 256, 0, stream>>>(row_ptr, gtail, gbk, cols);

    // ---- layer 1 ----
    gemm_mfma_k<true><<<gGemm, 256, 0, stream>>>(x, Wb1, b1, dinv, Yu1, Ys1, NN);
    {
        const unsigned short* cur = Ys1;
        for (int k = 0; k < 10; ++k) {
            unsigned short* dst = (k == 9) ? Hrelu : ((k & 1) ? HB : HA);
            appnp_h_k<<<gStep, 256, 0, stream>>>(cur, Yu1, dinv, dst, row_ptr,
                                                 cols, (k == 9) ? 1 : 0, W3, puv);
            cur = dst;
        }
    }
    // ---- layer 2 ----
    gemm_mfma_k<false><<<gGemm, 256, 0, stream>>>(Hrelu, Wb2, b2, dinv, Yu2, Ys2, NN);
    {
        const unsigned short* cur = Ys2;
        for (int k = 0; k < 10; ++k) {
            unsigned short* dst = (k & 1) ? HB : HA;
            appnp_h_k<<<gStep, 256, 0, stream>>>(cur, Yu2, dinv, dst, row_ptr,
                                                 cols, (k == 9) ? 2 : 0, W3, puv);
            cur = dst;
        }
    }
    // ---- pair head ----
    pair2_k<<<gPair, 256, 0, stream>>>(puv, (const int2*)idx, b3, out);
}